// Round 14
// baseline (613.387 us; speedup 1.0000x reference)
//
#include <hip/hip_runtime.h>

#define SEQ_LEN 96
#define PRED_LEN 16
#define HIDDEN 64
#define FEAT 7
#define BATCH 512
#define TL (SEQ_LEN + PRED_LEN)   // 112-row sliding timeline
#define XSTR 8                    // padded row stride

typedef float v2f __attribute__((ext_vector_type(2)));

#define L2E 1.4426950408889634f

// DPP pair-swap (0<->1, 2<->3, ...): quad_perm [1,0,3,2]. Pure VALU.
__device__ __forceinline__ float qp_xor1(float v) {
    return __int_as_float(__builtin_amdgcn_mov_dpp(__float_as_int(v), 0xB1, 0xF, 0xF, true));
}

// r9 skeleton (measured best: 539us / ~843 cyc/step) + targeted pair exchange:
//  - reduce: each lane receives ONLY its 2 activation-gates' partner partials
//    (2sel+2DPP+2sel+2add replaces 4DPP+4add+2sel).
//  - cell: s=1 (holds i,g) sends the single product i*g via one DPP; s=0
//    (holds f,o) owns c and writes h alone. Deletes the 2-DPP + 8-cndmask
//    canonicalization entirely.
// 13-round landscape: wall = 1536 x single-step critical path (barrier + LDS
// round trip + dot issue + act chain). sigma=4/sigma=1/no-barrier/MFMA/
// dual-batch/xg-precompute all regressed; this is the last identified fat.
// Block = 128 thr (2 waves) = ONE batch; grid 512 -> 2 blocks/CU staggered
// (r8 lesson), 1 wave/SIMD (r6 lesson). Thread (u=tid>>1, s=tid&1): all 4
// gates of unit u, K-half [32s,32s+32). One barrier/step; x-prefetch in the
// barrier shadow (r9 win).
__global__ __launch_bounds__(128)
__attribute__((amdgpu_waves_per_eu(1, 1)))
__attribute__((amdgpu_num_vgpr(256)))
void lstm_ar_kernel(
    const float* __restrict__ x,     // [B, 96, 7]
    const float* __restrict__ W_ih,  // [256, 7]
    const float* __restrict__ W_hh,  // [256, 64]
    const float* __restrict__ b_ih,  // [256]
    const float* __restrict__ b_hh,  // [256]
    const float* __restrict__ fc_W,  // [7, 64]
    const float* __restrict__ fc_b,  // [7]
    float* __restrict__ out)         // [B, 16, 7]
{
    __shared__ float xs[TL * XSTR];   // padded sliding timeline (pad slot = 0)
    __shared__ float hb0[HIDDEN];     // h ping-pong
    __shared__ float hb1[HIDDEN];
    __shared__ float fcw[FEAT * HIDDEN];
    __shared__ float fcb[FEAT];

    const int tid = threadIdx.x;
    const int b   = blockIdx.x;
    const int u   = tid >> 1;         // hidden unit 0..63
    const int s   = tid & 1;          // K-half / activation-role

    // ---- per-thread weights: 4 gates x 32 K-cols as 16 v2f each ----
    v2f wh[4][16];
    #pragma unroll
    for (int g = 0; g < 4; ++g) {
        const float* wr = W_hh + (u + (g << 6)) * HIDDEN + (s << 5);
        #pragma unroll
        for (int j = 0; j < 16; ++j) wh[g][j] = *(const v2f*)(wr + 2 * j);
    }
    v2f wx[4][2];                     // x-cols [4s, 4s+4); col 7 -> 0 (eats pad)
    #pragma unroll
    for (int g = 0; g < 4; ++g)
        #pragma unroll
        for (int i = 0; i < 2; ++i) {
            int c0 = (s << 2) + 2 * i, c1 = c0 + 1;
            wx[g][i].x = W_ih[(u + (g << 6)) * FEAT + c0];
            wx[g][i].y = (c1 < FEAT) ? W_ih[(u + (g << 6)) * FEAT + c1] : 0.0f;
        }
    float bias[4];                    // bias carried by s==0 only
    #pragma unroll
    for (int g = 0; g < 4; ++g)
        bias[g] = (s == 0) ? (b_ih[u + (g << 6)] + b_hh[u + (g << 6)]) : 0.0f;

    // act_b per-lane consts: s=0 -> gate o (sigmoid), s=1 -> gate g (tanh)
    const float bk  = (s == 1) ? (-2.0f * L2E) : (-L2E);
    const float bm  = (s == 1) ? 2.0f : 1.0f;
    const float bbc = (s == 1) ? -1.0f : 0.0f;

    // ---- stage timeline / fc / init ----
    for (int i = tid; i < TL * XSTR; i += 128) {
        int row = i >> 3, f = i & 7;
        float v = 0.0f;
        if (row < SEQ_LEN && f < FEAT) v = x[b * SEQ_LEN * FEAT + row * FEAT + f];
        xs[i] = v;
    }
    for (int i = tid; i < FEAT * HIDDEN; i += 128) fcw[i] = fc_W[i];
    if (tid < FEAT)   fcb[tid] = fc_b[tid];
    if (tid < HIDDEN) hb0[tid] = 0.0f;
    float c = 0.0f;                   // cell state: valid in s==0 lanes
    __syncthreads();

    // One step: consumes pre-fetched xv, reads hr, writes hw, prefetches the
    // x row `nrow` AFTER the h-write / BEFORE the barrier, returns it.
    auto step = [&](float4 xv, int nrow,
                    const float* __restrict__ hr, float* __restrict__ hw) -> float4 {
        const float4* h4 = (const float4*)(hr + (s << 5));

        v2f A0, A1, A2, A3;
        A0.x = bias[0]; A0.y = 0.0f;
        A1.x = bias[1]; A1.y = 0.0f;
        A2.x = bias[2]; A2.y = 0.0f;
        A3.x = bias[3]; A3.y = 0.0f;
        v2f xlo; xlo.x = xv.x; xlo.y = xv.y;
        v2f xhi; xhi.x = xv.z; xhi.y = xv.w;
        A0 = __builtin_elementwise_fma(wx[0][0], xlo, A0);
        A1 = __builtin_elementwise_fma(wx[1][0], xlo, A1);
        A2 = __builtin_elementwise_fma(wx[2][0], xlo, A2);
        A3 = __builtin_elementwise_fma(wx[3][0], xlo, A3);
        A0 = __builtin_elementwise_fma(wx[0][1], xhi, A0);
        A1 = __builtin_elementwise_fma(wx[1][1], xhi, A1);
        A2 = __builtin_elementwise_fma(wx[2][1], xhi, A2);
        A3 = __builtin_elementwise_fma(wx[3][1], xhi, A3);

        #pragma unroll
        for (int j = 0; j < 8; ++j) {
            float4 hv = h4[j];
            v2f hlo; hlo.x = hv.x; hlo.y = hv.y;
            v2f hhi; hhi.x = hv.z; hhi.y = hv.w;
            A0 = __builtin_elementwise_fma(wh[0][2*j],   hlo, A0);
            A1 = __builtin_elementwise_fma(wh[1][2*j],   hlo, A1);
            A2 = __builtin_elementwise_fma(wh[2][2*j],   hlo, A2);
            A3 = __builtin_elementwise_fma(wh[3][2*j],   hlo, A3);
            A0 = __builtin_elementwise_fma(wh[0][2*j+1], hhi, A0);
            A1 = __builtin_elementwise_fma(wh[1][2*j+1], hhi, A1);
            A2 = __builtin_elementwise_fma(wh[2][2*j+1], hhi, A2);
            A3 = __builtin_elementwise_fma(wh[3][2*j+1], hhi, A3);
        }

        // horizontal partials of all 4 gates over this lane's K-half
        float r0 = A0.x + A0.y, r1 = A1.x + A1.y;
        float r2 = A2.x + A2.y, r3 = A3.x + A3.y;

        // targeted exchange: send only the 2 partials the partner activates.
        // s=0 activates f(r1),o(r3); s=1 activates i(r0),g(r2).
        float sa = s ? r1 : r0;       // s=0 sends r0 (partner wants i), s=1 sends r1
        float sb = s ? r3 : r2;
        float ra = qp_xor1(sa);       // partner's partial of MY first act-gate
        float rb = qp_xor1(sb);
        float aa = (s ? r0 : r1) + ra;   // full sum: f | i  (sigmoid both lanes)
        float ab = (s ? r2 : r3) + rb;   // full sum: o | g  (sigmoid | tanh)

        float ea = __builtin_amdgcn_exp2f(aa * (-L2E));
        float va = __builtin_amdgcn_rcpf(1.0f + ea);  // sigmoid: gf | gi
        float eb = __builtin_amdgcn_exp2f(ab * bk);
        float rbv = __builtin_amdgcn_rcpf(1.0f + eb);
        float vb = fmaf(bm, rbv, bbc);                // go | gg

        // s=1 holds gi,gg -> one product crosses the pair; s=0 owns c and h
        float m  = va * vb;           // s=1: gi*gg (s=0: gf*go, unused)
        float mr = qp_xor1(m);        // s=0 receives gi*gg
        c = fmaf(va, c, mr);          // s=0: gf*c + gi*gg
        float e2 = __builtin_amdgcn_exp2f(c * (-2.0f * L2E));
        float rr = __builtin_amdgcn_rcpf(1.0f + e2);
        float th = fmaf(2.0f, rr, -1.0f);             // tanh(c)
        float h  = vb * th;           // s=0: go * tanh(c)

        if (s == 0) hw[u] = h;        // single writer per unit

        // prefetch next x row in the barrier shadow (independent of h)
        float4 nxt = *(const float4*)&xs[nrow * XSTR + (s << 2)];
        __syncthreads();              // the ONLY barrier per step
        return nxt;
    };

    for (int k = 0; k < PRED_LEN; ++k) {
        float4 xv = *(const float4*)&xs[k * XSTR + (s << 2)];   // row k (t=0)
        for (int t = 0; t < SEQ_LEN; t += 2) {
            xv = step(xv, k + t + 1, hb0, hb1);
            xv = step(xv, k + t + 2, hb1, hb0);   // t=94: prefetch row k+96 (<112, in-bounds)
        }
        // after 96 steps the latest h is in hb0

        // ---- prediction head: lanes 0..6 of wave 0 ----
        if (tid < FEAT) {
            float p0 = fcb[tid], p1 = 0.0f, p2 = 0.0f, p3 = 0.0f;
            const float4* hh = (const float4*)hb0;
            #pragma unroll
            for (int j = 0; j < 16; ++j) {
                float4 hv = hh[j];
                p0 = fmaf(fcw[tid * HIDDEN + 4*j + 0], hv.x, p0);
                p1 = fmaf(fcw[tid * HIDDEN + 4*j + 1], hv.y, p1);
                p2 = fmaf(fcw[tid * HIDDEN + 4*j + 2], hv.z, p2);
                p3 = fmaf(fcw[tid * HIDDEN + 4*j + 3], hv.w, p3);
            }
            float pred = (p0 + p1) + (p2 + p3);
            out[(b * PRED_LEN + k) * FEAT + tid] = pred;
            xs[(SEQ_LEN + k) * XSTR + tid] = pred;   // append (pad slot stays 0)
        }
        __syncthreads();
    }
}

extern "C" void kernel_launch(void* const* d_in, const int* in_sizes, int n_in,
                              void* d_out, int out_size, void* d_ws, size_t ws_size,
                              hipStream_t stream) {
    const float* x    = (const float*)d_in[0];
    const float* W_ih = (const float*)d_in[1];
    const float* W_hh = (const float*)d_in[2];
    const float* b_ih = (const float*)d_in[3];
    const float* b_hh = (const float*)d_in[4];
    const float* fc_W = (const float*)d_in[5];
    const float* fc_b = (const float*)d_in[6];
    float* out = (float*)d_out;

    lstm_ar_kernel<<<BATCH, 128, 0, stream>>>(x, W_ih, W_hh, b_ih, b_hh, fc_W, fc_b, out);
}